// Round 5
// baseline (552.725 us; speedup 1.0000x reference)
//
#include <hip/hip_runtime.h>
#include <hip/hip_bf16.h>
#include <stdint.h>

// Problem constants (K=4, OUT=4096, IN=4096, B=2, S=2048)
#define DIM_M 4096   // B*S rows of x
#define DIM_N 4096   // OUT
#define DIM_K 4096   // IN
#define BASE_STRIDE (DIM_N * DIM_K)  // elements per basis
#define NT (DIM_K / 64)              // 64 K-tiles of BK=64

typedef __bf16 bf16x8 __attribute__((ext_vector_type(8)));
typedef float floatx16 __attribute__((ext_vector_type(16)));
typedef unsigned short ushort8 __attribute__((ext_vector_type(8)));

__device__ __forceinline__ unsigned short f2bf(float f) {
    uint32_t u = __float_as_uint(f);
    uint32_t r = (u + 0x7FFFu + ((u >> 16) & 1u)) >> 16;  // RNE
    return (unsigned short)r;
}

// ---------------------------------------------------------------------------
// Fused prologue (unchanged, verified): blocks [0,8192) build W_bf16;
// [8192,16384) convert x fp32 -> bf16. 8 elems/thread, 16B stores.
// ---------------------------------------------------------------------------
__global__ __launch_bounds__(256) void prep_kernel(
        const int* __restrict__ bases, const float* __restrict__ alphas,
        const float* __restrict__ x,
        unsigned short* __restrict__ Wb, unsigned short* __restrict__ Xb) {
    const int bid = blockIdx.x;
    if (bid < 8192) {
        const long e = ((long)bid * 256 + threadIdx.x) * 8;
        const float a0 = alphas[0], a1 = alphas[1], a2 = alphas[2], a3 = alphas[3];
        const int4 p0 = *(const int4*)(bases + e);
        const int4 p1 = *(const int4*)(bases + e + 4);
        const int4 q0 = *(const int4*)(bases + BASE_STRIDE + e);
        const int4 q1 = *(const int4*)(bases + BASE_STRIDE + e + 4);
        const int4 r0 = *(const int4*)(bases + 2L * BASE_STRIDE + e);
        const int4 r1 = *(const int4*)(bases + 2L * BASE_STRIDE + e + 4);
        const int4 s0 = *(const int4*)(bases + 3L * BASE_STRIDE + e);
        const int4 s1 = *(const int4*)(bases + 3L * BASE_STRIDE + e + 4);
        ushort8 o;
        o[0] = f2bf(a0 * p0.x + a1 * q0.x + a2 * r0.x + a3 * s0.x);
        o[1] = f2bf(a0 * p0.y + a1 * q0.y + a2 * r0.y + a3 * s0.y);
        o[2] = f2bf(a0 * p0.z + a1 * q0.z + a2 * r0.z + a3 * s0.z);
        o[3] = f2bf(a0 * p0.w + a1 * q0.w + a2 * r0.w + a3 * s0.w);
        o[4] = f2bf(a0 * p1.x + a1 * q1.x + a2 * r1.x + a3 * s1.x);
        o[5] = f2bf(a0 * p1.y + a1 * q1.y + a2 * r1.y + a3 * s1.y);
        o[6] = f2bf(a0 * p1.z + a1 * q1.z + a2 * r1.z + a3 * s1.z);
        o[7] = f2bf(a0 * p1.w + a1 * q1.w + a2 * r1.w + a3 * s1.w);
        *(ushort8*)(Wb + e) = o;
    } else {
        const long e = ((long)(bid - 8192) * 256 + threadIdx.x) * 8;
        const float4 v0 = *(const float4*)(x + e);
        const float4 v1 = *(const float4*)(x + e + 4);
        ushort8 o;
        o[0] = f2bf(v0.x); o[1] = f2bf(v0.y); o[2] = f2bf(v0.z); o[3] = f2bf(v0.w);
        o[4] = f2bf(v1.x); o[5] = f2bf(v1.y); o[6] = f2bf(v1.z); o[7] = f2bf(v1.w);
        *(ushort8*)(Xb + e) = o;
    }
}

// ---------------------------------------------------------------------------
// Main GEMM, 256x256 tile / BK=64 / 8-wave, 4-PHASE schedule (R5).
//
// R3/R4 POST-MORTEM: read placement inside the 8-phase skeleton is neutral
// (12/4/8/0 == 16/0/8/0, both 139us gemm); a[4] slots spill (VGPR cap 128).
// Measured 5212 cyc/K-tile vs 2067 MFMA-ideal: the dominant cost is the
// PER-PHASE fixed overhead (16 block-wide barriers/iter at 1 block/CU,
// 2 waves/SIMD straggle). R5 halves the phase count: 2 phases per K-tile,
// 16-MFMA clusters, 8 barriers/iter. Register-neutral (same a[2]/b[2]).
//
// LDS: lds[buf][op A=0,B=1][half 0,1][128 rows x 64 cols bf16] = 128 KiB.
// Staged with global_load_lds width=16 (linear LDS dest = wave base + lane*16).
// Swizzle (T2): LDS(row, chunk) holds global chunk (chunk ^ (row&7)): write
// side pre-swizzles the per-lane GLOBAL source; read side XORs the chunk.
// Conflict-free b128 reads.
//
// Schedule per iteration (2 K-tiles, 4 phases):
//   PA1: dsr a0,b0,a1,b1 [16]; stage A0,A1(t+1)->buf1; BAR; 16 MFMA; BAR
//   PA2: dsr a2,a3 [8];        stage B0,B1(t+2)->buf0; vmcnt(4); BAR; 16 MFMA; BAR
//   PB1: dsr a0,b0,a1,b1;      stage A0,A1(t+2)->buf0; BAR; 16 MFMA; BAR
//   PB2: dsr a2,a3;            stage B0,B1(t+3)->buf1; vmcnt(4); BAR; 16 MFMA; BAR
//
// vmcnt ledger (steady state): enter iter with 4 outstanding (B0,B1(t+1));
// +4 (PA1) = 8; +4 (PA2) = 12; vmcnt(4) retires the 8 oldest = exactly tile
// t+1's halves -> PB1 may read buf1. Mirror for PB2 -> tile t+2 before next
// iter. Prologue: 12 loads, vmcnt(4) -> tile0's 8 landed. Last iter drains
// with vmcnt(0).
// WAR (all barrier-separated): B halves of a buf are last read in P?1 and
// restaged in P?2; A halves last read in P?2 and restaged in the NEXT phase
// (PB1 / next-PA1). No same-phase read+overwrite of any half.
//
// 32x32x16 layouts (HW-verified, absmax 4.0): A/B operand m(/n)=lane&31,
// k=(lane>>5)*8+j; C/D col=lane&31, row=(r&3)+8*(r>>2)+4*g32.
// ---------------------------------------------------------------------------
#define MFMA32 __builtin_amdgcn_mfma_f32_32x32x16_bf16
#define BAR()   __builtin_amdgcn_s_barrier()
#define PRIO1() __builtin_amdgcn_s_setprio(1)
#define PRIO0() __builtin_amdgcn_s_setprio(0)

__device__ __forceinline__ void stage_half(const unsigned short* __restrict__ gb,
        int grow0, int kbase, unsigned short* ld, int wave, int lane) {
#pragma unroll
    for (int r = 0; r < 2; ++r) {
        const int row = wave * 16 + r * 8 + (lane >> 3);       // local row in half
        const int ch  = (lane & 7) ^ (row & 7);                // pre-swizzled src chunk
        const unsigned short* g = gb + (size_t)(grow0 + row) * DIM_K + kbase + ch * 8;
        unsigned short* d = ld + (wave * 16 + r * 8) * 64;     // wave-uniform LDS base
        __builtin_amdgcn_global_load_lds(
            (const __attribute__((address_space(1))) unsigned int*)((const void*)g),
            (__attribute__((address_space(3))) unsigned int*)((void*)d), 16, 0, 0);
    }
}

#define DS_A(LD, MI, SLOT)                                                        \
    do { _Pragma("unroll") for (int k = 0; k < 4; ++k)                            \
        a[SLOT][k] = *(const bf16x8*)((LD) + ((MI) * 32 + l31) * 64 + cko[k]);    \
    } while (0)
#define DS_B(LD, NH, SLOT)                                                        \
    do { _Pragma("unroll") for (int k = 0; k < 4; ++k)                            \
        b[SLOT][k] = *(const bf16x8*)((LD) + (nloc + (NH) * 32 + l31) * 64 + cko[k]); \
    } while (0)
#define MM2(MI0, MI1, NH, SB)                                                     \
    do { _Pragma("unroll") for (int k = 0; k < 4; ++k) {                          \
        acc[MI0][NH] = MFMA32(a[0][k], b[SB][k], acc[MI0][NH], 0, 0, 0);          \
        acc[MI1][NH] = MFMA32(a[1][k], b[SB][k], acc[MI1][NH], 0, 0, 0);          \
    } } while (0)

__global__ __launch_bounds__(512, 2) void gemm_bt_kernel(
        const unsigned short* __restrict__ A, const unsigned short* __restrict__ Bt,
        float* __restrict__ C) {
    __shared__ __align__(16) unsigned short lds[2][2][2][128 * 64];  // 128 KiB

    const int t = threadIdx.x;
    const int wave = t >> 6, lane = t & 63;
    const int l31 = lane & 31, g32 = lane >> 5;
    const int wm = wave >> 2;            // 0..1  -> A half / row block of 128
    const int wn = wave & 3;             // 0..3  -> 64-col block
    const int nloc = (wn & 1) * 64;      // row offset inside B half (wn>>1)

    const int mBase = blockIdx.y * 256;
    const int nBase = blockIdx.x * 256;

    const unsigned short* LA0 = &lds[0][0][wm][0];
    const unsigned short* LA1 = &lds[1][0][wm][0];
    const unsigned short* LB0 = &lds[0][1][wn >> 1][0];
    const unsigned short* LB1 = &lds[1][1][wn >> 1][0];

    int cko[4];
#pragma unroll
    for (int k = 0; k < 4; ++k) cko[k] = ((k * 2 + g32) ^ (l31 & 7)) * 8;

    floatx16 acc[4][2] = {};
    bf16x8 a[2][4], b[2][4];

    // ---- prologue: tile0 -> buf0 (A0,A1,B0,B1); tile1 -> buf1 (B0,B1) ----
    stage_half(A,  mBase + 0,   0,  &lds[0][0][0][0], wave, lane);
    stage_half(A,  mBase + 128, 0,  &lds[0][0][1][0], wave, lane);
    stage_half(Bt, nBase + 0,   0,  &lds[0][1][0][0], wave, lane);
    stage_half(Bt, nBase + 128, 0,  &lds[0][1][1][0], wave, lane);
    stage_half(Bt, nBase + 0,   64, &lds[1][1][0][0], wave, lane);
    stage_half(Bt, nBase + 128, 64, &lds[1][1][1][0], wave, lane);
    asm volatile("s_waitcnt vmcnt(4)" ::: "memory");   // tile0 fully landed
    BAR();

    for (int i = 0; i < NT / 2; ++i) {
        const bool more = (i < NT / 2 - 1);
        const int t1k = (2 * i + 1) * 64;
        const int t2k = (2 * i + 2) * 64;
        const int t3k = (2 * i + 3) * 64;

        // ---- PA1: tile 2i, first half (b0 then b1) ----
        DS_A(LA0, 0, 0); DS_B(LB0, 0, 0); DS_A(LA0, 1, 1); DS_B(LB0, 1, 1);
        stage_half(A, mBase + 0,   t1k, &lds[1][0][0][0], wave, lane);   // A0(t+1)
        stage_half(A, mBase + 128, t1k, &lds[1][0][1][0], wave, lane);   // A1(t+1)
        BAR(); PRIO1(); MM2(0, 1, 0, 0); MM2(0, 1, 1, 1); PRIO0(); BAR();

        // ---- PA2: tile 2i, second half ----
        DS_A(LA0, 2, 0); DS_A(LA0, 3, 1);
        if (more) {
            stage_half(Bt, nBase + 0,   t2k, &lds[0][1][0][0], wave, lane);
            stage_half(Bt, nBase + 128, t2k, &lds[0][1][1][0], wave, lane);
            asm volatile("s_waitcnt vmcnt(4)" ::: "memory");
        } else {
            asm volatile("s_waitcnt vmcnt(0)" ::: "memory");
        }
        BAR(); PRIO1(); MM2(2, 3, 1, 1); MM2(2, 3, 0, 0); PRIO0(); BAR();

        // ---- PB1: tile 2i+1, first half ----
        DS_A(LA1, 0, 0); DS_B(LB1, 0, 0); DS_A(LA1, 1, 1); DS_B(LB1, 1, 1);
        if (more) {
            stage_half(A, mBase + 0,   t2k, &lds[0][0][0][0], wave, lane);
            stage_half(A, mBase + 128, t2k, &lds[0][0][1][0], wave, lane);
        }
        BAR(); PRIO1(); MM2(0, 1, 0, 0); MM2(0, 1, 1, 1); PRIO0(); BAR();

        // ---- PB2: tile 2i+1, second half ----
        DS_A(LA1, 2, 0); DS_A(LA1, 3, 1);
        if (more) {
            stage_half(Bt, nBase + 0,   t3k, &lds[1][1][0][0], wave, lane);
            stage_half(Bt, nBase + 128, t3k, &lds[1][1][1][0], wave, lane);
            asm volatile("s_waitcnt vmcnt(4)" ::: "memory");
        } else {
            asm volatile("s_waitcnt vmcnt(0)" ::: "memory");
        }
        BAR(); PRIO1(); MM2(2, 3, 1, 1); MM2(2, 3, 0, 0); PRIO0(); BAR();
    }

    // Epilogue: C/D layout col=lane&31, row=(r&3)+8*(r>>2)+4*g32
#pragma unroll
    for (int mi = 0; mi < 4; ++mi) {
#pragma unroll
        for (int nh = 0; nh < 2; ++nh) {
#pragma unroll
            for (int r = 0; r < 16; ++r) {
                const int row = mBase + wm * 128 + mi * 32 + (r & 3) + 8 * (r >> 2) + 4 * g32;
                const int col = nBase + wn * 64 + nh * 32 + l31;
                C[(size_t)row * DIM_N + col] = acc[mi][nh][r];
            }
        }
    }
}

// ---------------------------------------------------------------------------
// Fallback (only if workspace too small): direct fp32, one thread per output
// ---------------------------------------------------------------------------
__global__ __launch_bounds__(256) void naive_kernel(
        const float* __restrict__ x, const float* __restrict__ alphas,
        const int* __restrict__ bases, float* __restrict__ out) {
    const long o = (long)blockIdx.x * 256 + threadIdx.x;
    const int m = (int)(o >> 12), n = (int)(o & 4095);
    const float a0 = alphas[0], a1 = alphas[1], a2 = alphas[2], a3 = alphas[3];
    const float* xr = x + (long)m * DIM_K;
    const int* b0 = bases + (long)n * DIM_K;
    const int* b1 = b0 + BASE_STRIDE;
    const int* b2 = b1 + BASE_STRIDE;
    const int* b3 = b2 + BASE_STRIDE;
    float acc = 0.f;
    for (int i = 0; i < DIM_K; i++) {
        float w = a0 * b0[i] + a1 * b1[i] + a2 * b2[i] + a3 * b3[i];
        acc += xr[i] * w;
    }
    out[o] = acc;
}

extern "C" void kernel_launch(void* const* d_in, const int* in_sizes, int n_in,
                              void* d_out, int out_size, void* d_ws, size_t ws_size,
                              hipStream_t stream) {
    const float* x      = (const float*)d_in[0];
    const float* alphas = (const float*)d_in[1];
    const int*   bases  = (const int*)d_in[2];
    float* out = (float*)d_out;

    const size_t need = (size_t)2 * DIM_N * DIM_K + (size_t)2 * DIM_M * DIM_K; // 64 MB
    if (ws_size >= need) {
        unsigned short* Wb = (unsigned short*)d_ws;                    // [4096][4096] bf16
        unsigned short* Xb = (unsigned short*)d_ws + (size_t)DIM_N * DIM_K;
        prep_kernel<<<16384, 256, 0, stream>>>(bases, alphas, x, Wb, Xb);
        gemm_bt_kernel<<<dim3(DIM_N / 256, DIM_M / 256), 512, 0, stream>>>(Xb, Wb, out);
    } else {
        naive_kernel<<<(DIM_M * DIM_N) / 256, 256, 0, stream>>>(x, alphas, bases, out);
    }
}

// Round 6
// 530.920 us; speedup vs baseline: 1.0411x; 1.0411x over previous
//
#include <hip/hip_runtime.h>
#include <hip/hip_bf16.h>
#include <stdint.h>

// Problem constants (K=4, OUT=4096, IN=4096, B=2, S=2048)
#define DIM_M 4096   // B*S rows of x
#define DIM_N 4096   // OUT
#define DIM_K 4096   // IN
#define BASE_STRIDE (DIM_N * DIM_K)  // elements per basis
#define NT (DIM_K / 64)              // 64 K-tiles of BK=64

typedef __bf16 bf16x8 __attribute__((ext_vector_type(8)));
typedef float floatx4 __attribute__((ext_vector_type(4)));
typedef unsigned short ushort8 __attribute__((ext_vector_type(8)));

__device__ __forceinline__ unsigned short f2bf(float f) {
    uint32_t u = __float_as_uint(f);
    uint32_t r = (u + 0x7FFFu + ((u >> 16) & 1u)) >> 16;  // RNE
    return (unsigned short)r;
}

// ---------------------------------------------------------------------------
// Fused prologue (unchanged, verified): blocks [0,8192) build W_bf16;
// [8192,16384) convert x fp32 -> bf16. 8 elems/thread, 16B stores.
// ---------------------------------------------------------------------------
__global__ __launch_bounds__(256) void prep_kernel(
        const int* __restrict__ bases, const float* __restrict__ alphas,
        const float* __restrict__ x,
        unsigned short* __restrict__ Wb, unsigned short* __restrict__ Xb) {
    const int bid = blockIdx.x;
    if (bid < 8192) {
        const long e = ((long)bid * 256 + threadIdx.x) * 8;
        const float a0 = alphas[0], a1 = alphas[1], a2 = alphas[2], a3 = alphas[3];
        const int4 p0 = *(const int4*)(bases + e);
        const int4 p1 = *(const int4*)(bases + e + 4);
        const int4 q0 = *(const int4*)(bases + BASE_STRIDE + e);
        const int4 q1 = *(const int4*)(bases + BASE_STRIDE + e + 4);
        const int4 r0 = *(const int4*)(bases + 2L * BASE_STRIDE + e);
        const int4 r1 = *(const int4*)(bases + 2L * BASE_STRIDE + e + 4);
        const int4 s0 = *(const int4*)(bases + 3L * BASE_STRIDE + e);
        const int4 s1 = *(const int4*)(bases + 3L * BASE_STRIDE + e + 4);
        ushort8 o;
        o[0] = f2bf(a0 * p0.x + a1 * q0.x + a2 * r0.x + a3 * s0.x);
        o[1] = f2bf(a0 * p0.y + a1 * q0.y + a2 * r0.y + a3 * s0.y);
        o[2] = f2bf(a0 * p0.z + a1 * q0.z + a2 * r0.z + a3 * s0.z);
        o[3] = f2bf(a0 * p0.w + a1 * q0.w + a2 * r0.w + a3 * s0.w);
        o[4] = f2bf(a0 * p1.x + a1 * q1.x + a2 * r1.x + a3 * s1.x);
        o[5] = f2bf(a0 * p1.y + a1 * q1.y + a2 * r1.y + a3 * s1.y);
        o[6] = f2bf(a0 * p1.z + a1 * q1.z + a2 * r1.z + a3 * s1.z);
        o[7] = f2bf(a0 * p1.w + a1 * q1.w + a2 * r1.w + a3 * s1.w);
        *(ushort8*)(Wb + e) = o;
    } else {
        const long e = ((long)(bid - 8192) * 256 + threadIdx.x) * 8;
        const float4 v0 = *(const float4*)(x + e);
        const float4 v1 = *(const float4*)(x + e + 4);
        ushort8 o;
        o[0] = f2bf(v0.x); o[1] = f2bf(v0.y); o[2] = f2bf(v0.z); o[3] = f2bf(v0.w);
        o[4] = f2bf(v1.x); o[5] = f2bf(v1.y); o[6] = f2bf(v1.z); o[7] = f2bf(v1.w);
        *(ushort8*)(Xb + e) = o;
    }
}

// ---------------------------------------------------------------------------
// Main GEMM, 256x256 tile / BK=64 / 8-wave / 8-phase schedule.
//
// R6: SAME verified sync skeleton as R2 (stage placement, vmcnt(6) ledger,
// WAR distances, chunk^row&7 swizzle, barriers, setprio) — compute core
// swapped from 32x32x16 (2x2 acc, 8-MFMA phases, dep distance 2) to the
// documented m201 decomposition: mfma_f32_16x16x32, per-wave 8x4 frag accs
// (f32x4, 128 VGPR — identical budget), quadrant phases Q00->Q01->Q11->Q10
// with reads 12/4/8/0 and 16-MFMA clusters (kh-outer: dep distance 8).
// R3-R5 showed read placement / phase count are neutral; this isolates the
// MFMA granularity variable (m198 linear-LDS 8-phase = 1167 TF > our 990
// conflict-free -> the gap is in cluster shape, not banks).
//
// LDS: lds[buf][op A=0,B=1][half 0,1][128 rows x 64 cols bf16] = 128 KiB.
// Staged with global_load_lds width=16 (linear LDS dest = wave base+lane*16).
// Swizzle: LDS(row, chunk) holds global chunk (chunk ^ (row&7)); write side
// pre-swizzles the per-lane GLOBAL source; read side XORs the chunk.
// 16x16x32 frag read: row = f*16+(lane&15), chunk = (lane>>4)+4*kh; bank
// quad = chunk^(lane&7) spreads 64 lanes to 8 quads x 8 distinct rows =
// b128 bandwidth floor (same as the 32x32 pattern).
//
// Schedule per K-tile t (4 phases), 2 tiles per loop iteration:
//   P1: dsr A(mf0-3)x2kh + B(nf0-1)x2kh [12]; stage A1(t+1); 16 MFMA Q00
//   P2: dsr B(nf2-3)x2kh [4];                               16 MFMA Q01
//   P3: dsr A(mf4-7)x2kh [8]; stage B0(t+2);                16 MFMA Q11
//   P4: stage B1,A0(t+2); vmcnt(6);                         16 MFMA Q10
// Each phase: [dsr; stage; s_barrier; setprio(1); MFMA; setprio(0); s_barrier]
//
// vmcnt ledger (identical to R2, verified): steady state enters iter with 6
// outstanding (next tile's B0,B1,A0); +2 (P1) +2 (P3) +4 (P4) = 14; vmcnt(6)
// retires the 8 oldest = exactly the next tile. Last iter drains vmcnt(0).
// WAR (identical): A-half reads end P3, restaged P4/PB1; B-half reads end
// P2, restaged P3/P4 — all >=1 barrier after last read.
//
// 16x16x32 layouts: A/B operand m(/n)=lane&15, k=(lane>>4)*8+j;
// C/D col=lane&15, row=(lane>>4)*4+reg (m89-verified, dtype-independent).
// ---------------------------------------------------------------------------
#define MFMA16 __builtin_amdgcn_mfma_f32_16x16x32_bf16
#define BAR()   __builtin_amdgcn_s_barrier()
#define PRIO1() __builtin_amdgcn_s_setprio(1)
#define PRIO0() __builtin_amdgcn_s_setprio(0)

__device__ __forceinline__ void stage_half(const unsigned short* __restrict__ gb,
        int grow0, int kbase, unsigned short* ld, int wave, int lane) {
#pragma unroll
    for (int r = 0; r < 2; ++r) {
        const int row = wave * 16 + r * 8 + (lane >> 3);       // local row in half
        const int ch  = (lane & 7) ^ (row & 7);                // pre-swizzled src chunk
        const unsigned short* g = gb + (size_t)(grow0 + row) * DIM_K + kbase + ch * 8;
        unsigned short* d = ld + (wave * 16 + r * 8) * 64;     // wave-uniform LDS base
        __builtin_amdgcn_global_load_lds(
            (const __attribute__((address_space(1))) unsigned int*)((const void*)g),
            (__attribute__((address_space(3))) unsigned int*)((void*)d), 16, 0, 0);
    }
}

// Load one 16-row fragment pair (both k-halves) for A (row base MF*16)
#define DS_A16(LD, MF, SLOT)                                                          \
    do {                                                                              \
        aR[SLOT][0] = *(const bf16x8*)((LD) + ((MF) * 16 + l15) * 64 + cko2[0]);      \
        aR[SLOT][1] = *(const bf16x8*)((LD) + ((MF) * 16 + l15) * 64 + cko2[1]);      \
    } while (0)
// and for B (row base nloc + NF*16)
#define DS_B16(LD, NF, SLOT)                                                          \
    do {                                                                              \
        bR[SLOT][0] = *(const bf16x8*)((LD) + (nloc + (NF) * 16 + l15) * 64 + cko2[0]); \
        bR[SLOT][1] = *(const bf16x8*)((LD) + (nloc + (NF) * 16 + l15) * 64 + cko2[1]); \
    } while (0)
// One C-quadrant x K=64: 16 MFMA, kh-outer (dep distance 8 per acc chain)
#define MMQ(MB, NB)                                                                   \
    do { _Pragma("unroll") for (int kh = 0; kh < 2; ++kh)                             \
        _Pragma("unroll") for (int n = 0; n < 2; ++n)                                 \
            _Pragma("unroll") for (int m = 0; m < 4; ++m)                             \
                acc4[(MB) + m][(NB) + n] = MFMA16(aR[m][kh], bR[(NB) + n][kh],        \
                                                  acc4[(MB) + m][(NB) + n], 0, 0, 0); \
    } while (0)

__global__ __launch_bounds__(512, 2) void gemm_bt_kernel(
        const unsigned short* __restrict__ A, const unsigned short* __restrict__ Bt,
        float* __restrict__ C) {
    __shared__ __align__(16) unsigned short lds[2][2][2][128 * 64];  // 128 KiB

    const int t = threadIdx.x;
    const int wave = t >> 6, lane = t & 63;
    const int l15 = lane & 15, l4 = lane >> 4;     // 16x16 frag coords
    const int wm = wave >> 2;            // 0..1  -> A half / row block of 128
    const int wn = wave & 3;             // 0..3  -> 64-col block
    const int nloc = (wn & 1) * 64;      // row offset inside B half (wn>>1)

    const int mBase = blockIdx.y * 256;
    const int nBase = blockIdx.x * 256;

    const unsigned short* LA0 = &lds[0][0][wm][0];
    const unsigned short* LA1 = &lds[1][0][wm][0];
    const unsigned short* LB0 = &lds[0][1][wn >> 1][0];
    const unsigned short* LB1 = &lds[1][1][wn >> 1][0];

    int cko2[2];
#pragma unroll
    for (int kh = 0; kh < 2; ++kh) cko2[kh] = ((l4 + 4 * kh) ^ (l15 & 7)) * 8;

    floatx4 acc4[8][4] = {};
    bf16x8 aR[4][2], bR[4][2];

    // ---- prologue: tile0 -> buf0 (A0,A1,B0,B1); tile1 -> buf1 (B0,B1,A0) ----
    stage_half(A,  mBase + 0,   0,  &lds[0][0][0][0], wave, lane);
    stage_half(A,  mBase + 128, 0,  &lds[0][0][1][0], wave, lane);
    stage_half(Bt, nBase + 0,   0,  &lds[0][1][0][0], wave, lane);
    stage_half(Bt, nBase + 128, 0,  &lds[0][1][1][0], wave, lane);
    stage_half(Bt, nBase + 0,   64, &lds[1][1][0][0], wave, lane);
    stage_half(Bt, nBase + 128, 64, &lds[1][1][1][0], wave, lane);
    stage_half(A,  mBase + 0,   64, &lds[1][0][0][0], wave, lane);
    asm volatile("s_waitcnt vmcnt(6)" ::: "memory");   // tile0 fully landed
    BAR();

    for (int i = 0; i < NT / 2; ++i) {
        const bool more = (i < NT / 2 - 1);
        const int t1k = (2 * i + 1) * 64;
        const int t2k = (2 * i + 2) * 64;
        const int t3k = (2 * i + 3) * 64;

        // ================= group A: tile 2i from buf0 =================
        // P1: A mf0-3 (both kh) + B nf0-1 (both kh) = 12 reads; Q00
        DS_A16(LA0, 0, 0); DS_A16(LA0, 1, 1); DS_A16(LA0, 2, 2); DS_A16(LA0, 3, 3);
        DS_B16(LB0, 0, 0); DS_B16(LB0, 1, 1);
        stage_half(A, mBase + 128, t1k, &lds[1][0][1][0], wave, lane);   // A1(t+1)
        BAR(); PRIO1(); MMQ(0, 0); PRIO0(); BAR();
        // P2: B nf2-3 = 4 reads; Q01
        DS_B16(LB0, 2, 2); DS_B16(LB0, 3, 3);
        BAR(); PRIO1(); MMQ(0, 2); PRIO0(); BAR();
        // P3: A mf4-7 = 8 reads (reuse slots 0-3); Q11
        DS_A16(LA0, 4, 0); DS_A16(LA0, 5, 1); DS_A16(LA0, 6, 2); DS_A16(LA0, 7, 3);
        if (more) stage_half(Bt, nBase + 0, t2k, &lds[0][1][0][0], wave, lane);
        BAR(); PRIO1(); MMQ(4, 2); PRIO0(); BAR();
        // P4: no reads; Q10 (bR[0..1] live since P1)
        if (more) {
            stage_half(Bt, nBase + 128, t2k, &lds[0][1][1][0], wave, lane);
            stage_half(A,  mBase + 0,   t2k, &lds[0][0][0][0], wave, lane);
            asm volatile("s_waitcnt vmcnt(6)" ::: "memory");
        } else {
            asm volatile("s_waitcnt vmcnt(0)" ::: "memory");
        }
        BAR(); PRIO1(); MMQ(4, 0); PRIO0(); BAR();

        // ================= group B: tile 2i+1 from buf1 =================
        // P1
        DS_A16(LA1, 0, 0); DS_A16(LA1, 1, 1); DS_A16(LA1, 2, 2); DS_A16(LA1, 3, 3);
        DS_B16(LB1, 0, 0); DS_B16(LB1, 1, 1);
        if (more) stage_half(A, mBase + 128, t2k, &lds[0][0][1][0], wave, lane); // A1(t+2)
        BAR(); PRIO1(); MMQ(0, 0); PRIO0(); BAR();
        // P2
        DS_B16(LB1, 2, 2); DS_B16(LB1, 3, 3);
        BAR(); PRIO1(); MMQ(0, 2); PRIO0(); BAR();
        // P3
        DS_A16(LA1, 4, 0); DS_A16(LA1, 5, 1); DS_A16(LA1, 6, 2); DS_A16(LA1, 7, 3);
        if (more) stage_half(Bt, nBase + 0, t3k, &lds[1][1][0][0], wave, lane);
        BAR(); PRIO1(); MMQ(4, 2); PRIO0(); BAR();
        // P4
        if (more) {
            stage_half(Bt, nBase + 128, t3k, &lds[1][1][1][0], wave, lane);
            stage_half(A,  mBase + 0,   t3k, &lds[1][0][0][0], wave, lane);
            asm volatile("s_waitcnt vmcnt(6)" ::: "memory");
        } else {
            asm volatile("s_waitcnt vmcnt(0)" ::: "memory");
        }
        BAR(); PRIO1(); MMQ(4, 0); PRIO0(); BAR();
    }

    // Epilogue: 16x16 C/D layout col=lane&15, row=(lane>>4)*4+reg
#pragma unroll
    for (int mf = 0; mf < 8; ++mf) {
#pragma unroll
        for (int nf = 0; nf < 4; ++nf) {
#pragma unroll
            for (int r = 0; r < 4; ++r) {
                const int row = mBase + wm * 128 + mf * 16 + l4 * 4 + r;
                const int col = nBase + wn * 64 + nf * 16 + l15;
                C[(size_t)row * DIM_N + col] = acc4[mf][nf][r];
            }
        }
    }
}

// ---------------------------------------------------------------------------
// Fallback (only if workspace too small): direct fp32, one thread per output
// ---------------------------------------------------------------------------
__global__ __launch_bounds__(256) void naive_kernel(
        const float* __restrict__ x, const float* __restrict__ alphas,
        const int* __restrict__ bases, float* __restrict__ out) {
    const long o = (long)blockIdx.x * 256 + threadIdx.x;
    const int m = (int)(o >> 12), n = (int)(o & 4095);
    const float a0 = alphas[0], a1 = alphas[1], a2 = alphas[2], a3 = alphas[3];
    const float* xr = x + (long)m * DIM_K;
    const int* b0 = bases + (long)n * DIM_K;
    const int* b1 = b0 + BASE_STRIDE;
    const int* b2 = b1 + BASE_STRIDE;
    const int* b3 = b2 + BASE_STRIDE;
    float acc = 0.f;
    for (int i = 0; i < DIM_K; i++) {
        float w = a0 * b0[i] + a1 * b1[i] + a2 * b2[i] + a3 * b3[i];
        acc += xr[i] * w;
    }
    out[o] = acc;
}

extern "C" void kernel_launch(void* const* d_in, const int* in_sizes, int n_in,
                              void* d_out, int out_size, void* d_ws, size_t ws_size,
                              hipStream_t stream) {
    const float* x      = (const float*)d_in[0];
    const float* alphas = (const float*)d_in[1];
    const int*   bases  = (const int*)d_in[2];
    float* out = (float*)d_out;

    const size_t need = (size_t)2 * DIM_N * DIM_K + (size_t)2 * DIM_M * DIM_K; // 64 MB
    if (ws_size >= need) {
        unsigned short* Wb = (unsigned short*)d_ws;                    // [4096][4096] bf16
        unsigned short* Xb = (unsigned short*)d_ws + (size_t)DIM_N * DIM_K;
        prep_kernel<<<16384, 256, 0, stream>>>(bases, alphas, x, Wb, Xb);
        gemm_bt_kernel<<<dim3(DIM_N / 256, DIM_M / 256), 512, 0, stream>>>(Xb, Wb, out);
    } else {
        naive_kernel<<<(DIM_M * DIM_N) / 256, 256, 0, stream>>>(x, alphas, bases, out);
    }
}

// Round 7
// 529.140 us; speedup vs baseline: 1.0446x; 1.0034x over previous
//
#include <hip/hip_runtime.h>
#include <hip/hip_bf16.h>
#include <stdint.h>

// Problem constants (K=4, OUT=4096, IN=4096, B=2, S=2048)
#define DIM_M 4096   // B*S rows of x
#define DIM_N 4096   // OUT
#define DIM_K 4096   // IN
#define BASE_STRIDE (DIM_N * DIM_K)  // elements per basis
#define NT (DIM_K / 64)              // 64 K-tiles of BK=64

typedef __bf16 bf16x8 __attribute__((ext_vector_type(8)));
typedef float floatx4 __attribute__((ext_vector_type(4)));
typedef unsigned short ushort8 __attribute__((ext_vector_type(8)));

__device__ __forceinline__ unsigned short f2bf(float f) {
    uint32_t u = __float_as_uint(f);
    uint32_t r = (u + 0x7FFFu + ((u >> 16) & 1u)) >> 16;  // RNE
    return (unsigned short)r;
}

// ---------------------------------------------------------------------------
// Fused prologue (unchanged, verified): blocks [0,8192) build W_bf16;
// [8192,16384) convert x fp32 -> bf16. 8 elems/thread, 16B stores.
// ---------------------------------------------------------------------------
__global__ __launch_bounds__(256) void prep_kernel(
        const int* __restrict__ bases, const float* __restrict__ alphas,
        const float* __restrict__ x,
        unsigned short* __restrict__ Wb, unsigned short* __restrict__ Xb) {
    const int bid = blockIdx.x;
    if (bid < 8192) {
        const long e = ((long)bid * 256 + threadIdx.x) * 8;
        const float a0 = alphas[0], a1 = alphas[1], a2 = alphas[2], a3 = alphas[3];
        const int4 p0 = *(const int4*)(bases + e);
        const int4 p1 = *(const int4*)(bases + e + 4);
        const int4 q0 = *(const int4*)(bases + BASE_STRIDE + e);
        const int4 q1 = *(const int4*)(bases + BASE_STRIDE + e + 4);
        const int4 r0 = *(const int4*)(bases + 2L * BASE_STRIDE + e);
        const int4 r1 = *(const int4*)(bases + 2L * BASE_STRIDE + e + 4);
        const int4 s0 = *(const int4*)(bases + 3L * BASE_STRIDE + e);
        const int4 s1 = *(const int4*)(bases + 3L * BASE_STRIDE + e + 4);
        ushort8 o;
        o[0] = f2bf(a0 * p0.x + a1 * q0.x + a2 * r0.x + a3 * s0.x);
        o[1] = f2bf(a0 * p0.y + a1 * q0.y + a2 * r0.y + a3 * s0.y);
        o[2] = f2bf(a0 * p0.z + a1 * q0.z + a2 * r0.z + a3 * s0.z);
        o[3] = f2bf(a0 * p0.w + a1 * q0.w + a2 * r0.w + a3 * s0.w);
        o[4] = f2bf(a0 * p1.x + a1 * q1.x + a2 * r1.x + a3 * s1.x);
        o[5] = f2bf(a0 * p1.y + a1 * q1.y + a2 * r1.y + a3 * s1.y);
        o[6] = f2bf(a0 * p1.z + a1 * q1.z + a2 * r1.z + a3 * s1.z);
        o[7] = f2bf(a0 * p1.w + a1 * q1.w + a2 * r1.w + a3 * s1.w);
        *(ushort8*)(Wb + e) = o;
    } else {
        const long e = ((long)(bid - 8192) * 256 + threadIdx.x) * 8;
        const float4 v0 = *(const float4*)(x + e);
        const float4 v1 = *(const float4*)(x + e + 4);
        ushort8 o;
        o[0] = f2bf(v0.x); o[1] = f2bf(v0.y); o[2] = f2bf(v0.z); o[3] = f2bf(v0.w);
        o[4] = f2bf(v1.x); o[5] = f2bf(v1.y); o[6] = f2bf(v1.z); o[7] = f2bf(v1.w);
        *(ushort8*)(Xb + e) = o;
    }
}

// ---------------------------------------------------------------------------
// Main GEMM, 256x256 tile / BK=64 / 8-wave / 16x16x32 MFMA (R7).
//
// R6 POST-MORTEM (cycle model closes): 4785 cyc/K-tile measured =
// MFMA 2061 + LDS-read ~2700 FULLY SERIALIZED, because every phase was
// {reads -> BAR -> lgkmcnt(0) -> MFMA -> BAR}: same-phase consumption idles
// the LDS pipe during MFMA and vice versa. R3/R4/R5 were neutral because
// they only moved reads WITHIN that skeleton.
//
// R7: every ds_read lands ONE PHASE before consumption, zero new registers:
//   P1: [reads B2-3 (slots free)]; stage A1(t+1); Q00 MFMA (frags from P4);
//       BAR
//   P2: Q01 MFMA (b2-3 from P1); [reads A4-7 -> slots a0-3, POST-cluster:
//       Q01 just consumed a0-3, in-order issue makes reg-WAR safe]; BAR
//   P3: stage B0(t+2); Q11 MFMA (a=A4-7 from P2); BAR
//   P4: stage B1,A0(t+2); vmcnt(6); BAR(mid, RAW for next buf);
//       Q10 MFMA; [boundary reads: next-tile A0-3,B0-1, POST-cluster:
//       Q10 just consumed those slots]; BAR
// 5 barriers/tile (was 8). LDS reads now execute under MFMA clusters
// (own wave's cluster tail + other wave's cluster).
//
// vmcnt ledger (re-derived): tile t's halves issue as B0@(t-2)P3,
// B1@(t-2)P4, A0@(t-2)P4, A1@(t-1)P1. At (t-1)P4 after its stage issue:
// 14 outstanding; vmcnt(6) retires oldest 8 = exactly tile t -> mid-BAR ->
// boundary reads of buf(t) safe. Prologue: 14 loads (t0 all, t1 B0,B1,A0),
// vmcnt(6) retires t0's 8, BAR, read Q00(t0). Last iter: vmcnt(0), group B
// skips boundary reads.
// WAR audit (1-barrier phases): every region's last ds_read is drained
// (compiler lgkmcnt before the reading wave's next cluster) >=1 full
// barrier before any restage ISSUE: B-halves last read P1 (B2-3), restaged
// P3/P4; A-halves last read P2-end (A4-7), restaged P4/next-P1; boundary
// reads (P4-end) drained by P1's cluster, restaged >= next P1/P3.
//
// LDS layout + swizzle unchanged (verified): lds[buf][A,B][half][128x64],
// global_load_lds w16 linear dest, chunk^(row&7) pre-swizzled source,
// read-side XOR -> 8 words/bank floor.
// 16x16x32 layouts (HW-verified): A/B operand m(/n)=lane&15, k=(lane>>4)*8+j;
// C/D col=lane&15, row=(lane>>4)*4+reg.
// ---------------------------------------------------------------------------
#define MFMA16 __builtin_amdgcn_mfma_f32_16x16x32_bf16
#define BAR()   __builtin_amdgcn_s_barrier()
#define PRIO1() __builtin_amdgcn_s_setprio(1)
#define PRIO0() __builtin_amdgcn_s_setprio(0)

__device__ __forceinline__ void stage_half(const unsigned short* __restrict__ gb,
        int grow0, int kbase, unsigned short* ld, int wave, int lane) {
#pragma unroll
    for (int r = 0; r < 2; ++r) {
        const int row = wave * 16 + r * 8 + (lane >> 3);       // local row in half
        const int ch  = (lane & 7) ^ (row & 7);                // pre-swizzled src chunk
        const unsigned short* g = gb + (size_t)(grow0 + row) * DIM_K + kbase + ch * 8;
        unsigned short* d = ld + (wave * 16 + r * 8) * 64;     // wave-uniform LDS base
        __builtin_amdgcn_global_load_lds(
            (const __attribute__((address_space(1))) unsigned int*)((const void*)g),
            (__attribute__((address_space(3))) unsigned int*)((void*)d), 16, 0, 0);
    }
}

// Load one 16-row fragment pair (both k-halves) for A (row base MF*16)
#define DS_A16(LD, MF, SLOT)                                                          \
    do {                                                                              \
        aR[SLOT][0] = *(const bf16x8*)((LD) + ((MF) * 16 + l15) * 64 + cko2[0]);      \
        aR[SLOT][1] = *(const bf16x8*)((LD) + ((MF) * 16 + l15) * 64 + cko2[1]);      \
    } while (0)
// and for B (row base nloc + NF*16)
#define DS_B16(LD, NF, SLOT)                                                          \
    do {                                                                              \
        bR[SLOT][0] = *(const bf16x8*)((LD) + (nloc + (NF) * 16 + l15) * 64 + cko2[0]); \
        bR[SLOT][1] = *(const bf16x8*)((LD) + (nloc + (NF) * 16 + l15) * 64 + cko2[1]); \
    } while (0)
// One C-quadrant x K=64: 16 MFMA, kh-outer (dep distance 8 per acc chain)
#define MMQ(MB, NB)                                                                   \
    do { _Pragma("unroll") for (int kh = 0; kh < 2; ++kh)                             \
        _Pragma("unroll") for (int n = 0; n < 2; ++n)                                 \
            _Pragma("unroll") for (int m = 0; m < 4; ++m)                             \
                acc4[(MB) + m][(NB) + n] = MFMA16(aR[m][kh], bR[(NB) + n][kh],        \
                                                  acc4[(MB) + m][(NB) + n], 0, 0, 0); \
    } while (0)

__global__ __launch_bounds__(512, 2) void gemm_bt_kernel(
        const unsigned short* __restrict__ A, const unsigned short* __restrict__ Bt,
        float* __restrict__ C) {
    __shared__ __align__(16) unsigned short lds[2][2][2][128 * 64];  // 128 KiB

    const int t = threadIdx.x;
    const int wave = t >> 6, lane = t & 63;
    const int l15 = lane & 15, l4 = lane >> 4;     // 16x16 frag coords
    const int wm = wave >> 2;            // 0..1  -> A half / row block of 128
    const int wn = wave & 3;             // 0..3  -> 64-col block
    const int nloc = (wn & 1) * 64;      // row offset inside B half (wn>>1)

    const int mBase = blockIdx.y * 256;
    const int nBase = blockIdx.x * 256;

    const unsigned short* LA0 = &lds[0][0][wm][0];
    const unsigned short* LA1 = &lds[1][0][wm][0];
    const unsigned short* LB0 = &lds[0][1][wn >> 1][0];
    const unsigned short* LB1 = &lds[1][1][wn >> 1][0];

    int cko2[2];
#pragma unroll
    for (int kh = 0; kh < 2; ++kh) cko2[kh] = ((l4 + 4 * kh) ^ (l15 & 7)) * 8;

    floatx4 acc4[8][4] = {};
    bf16x8 aR[4][2], bR[4][2];

    // ---- prologue: tile0 -> buf0 (all 4 halves); tile1 -> buf1 (B0,B1,A0) ----
    stage_half(A,  mBase + 0,   0,  &lds[0][0][0][0], wave, lane);
    stage_half(A,  mBase + 128, 0,  &lds[0][0][1][0], wave, lane);
    stage_half(Bt, nBase + 0,   0,  &lds[0][1][0][0], wave, lane);
    stage_half(Bt, nBase + 128, 0,  &lds[0][1][1][0], wave, lane);
    stage_half(Bt, nBase + 0,   64, &lds[1][1][0][0], wave, lane);
    stage_half(Bt, nBase + 128, 64, &lds[1][1][1][0], wave, lane);
    stage_half(A,  mBase + 0,   64, &lds[1][0][0][0], wave, lane);
    asm volatile("s_waitcnt vmcnt(6)" ::: "memory");   // tile0 fully landed
    BAR();
    // boundary reads for tile0's Q00 (consumed in first PA1)
    DS_A16(LA0, 0, 0); DS_A16(LA0, 1, 1); DS_A16(LA0, 2, 2); DS_A16(LA0, 3, 3);
    DS_B16(LB0, 0, 0); DS_B16(LB0, 1, 1);

    for (int i = 0; i < NT / 2; ++i) {
        const bool more = (i < NT / 2 - 1);
        const int t1k = (2 * i + 1) * 64;
        const int t2k = (2 * i + 2) * 64;
        const int t3k = (2 * i + 3) * 64;

        // ================= group A: tile 2i from buf0 =================
        // P1: Q00 (frags pre-read at prev P4-end); pre-read B2-3 (free slots)
        DS_B16(LB0, 2, 2); DS_B16(LB0, 3, 3);
        stage_half(A, mBase + 128, t1k, &lds[1][0][1][0], wave, lane);   // A1(t+1)
        PRIO1(); MMQ(0, 0); PRIO0();
        BAR();
        // P2: Q01 (b2-3 landed under P1); post-read A4-7 into freed a0-3
        PRIO1(); MMQ(0, 2); PRIO0();
        DS_A16(LA0, 4, 0); DS_A16(LA0, 5, 1); DS_A16(LA0, 6, 2); DS_A16(LA0, 7, 3);
        BAR();
        // P3: Q11 (A4-7 landed under P2/barrier)
        if (more) stage_half(Bt, nBase + 0, t2k, &lds[0][1][0][0], wave, lane);
        PRIO1(); MMQ(4, 2); PRIO0();
        BAR();
        // P4: stage; vmcnt; mid-BAR (RAW for buf1); Q10; boundary reads (buf1)
        if (more) {
            stage_half(Bt, nBase + 128, t2k, &lds[0][1][1][0], wave, lane);
            stage_half(A,  mBase + 0,   t2k, &lds[0][0][0][0], wave, lane);
            asm volatile("s_waitcnt vmcnt(6)" ::: "memory");
        } else {
            asm volatile("s_waitcnt vmcnt(0)" ::: "memory");
        }
        BAR();
        PRIO1(); MMQ(4, 0); PRIO0();
        DS_A16(LA1, 0, 0); DS_A16(LA1, 1, 1); DS_A16(LA1, 2, 2); DS_A16(LA1, 3, 3);
        DS_B16(LB1, 0, 0); DS_B16(LB1, 1, 1);
        BAR();

        // ================= group B: tile 2i+1 from buf1 =================
        // P1
        DS_B16(LB1, 2, 2); DS_B16(LB1, 3, 3);
        if (more) stage_half(A, mBase + 128, t2k, &lds[0][0][1][0], wave, lane); // A1(t+2)
        PRIO1(); MMQ(0, 0); PRIO0();
        BAR();
        // P2
        PRIO1(); MMQ(0, 2); PRIO0();
        DS_A16(LA1, 4, 0); DS_A16(LA1, 5, 1); DS_A16(LA1, 6, 2); DS_A16(LA1, 7, 3);
        BAR();
        // P3
        if (more) stage_half(Bt, nBase + 0, t3k, &lds[1][1][0][0], wave, lane);
        PRIO1(); MMQ(4, 2); PRIO0();
        BAR();
        // P4
        if (more) {
            stage_half(Bt, nBase + 128, t3k, &lds[1][1][1][0], wave, lane);
            stage_half(A,  mBase + 0,   t3k, &lds[1][0][0][0], wave, lane);
            asm volatile("s_waitcnt vmcnt(6)" ::: "memory");
        } else {
            asm volatile("s_waitcnt vmcnt(0)" ::: "memory");
        }
        BAR();
        PRIO1(); MMQ(4, 0); PRIO0();
        if (more) {
            DS_A16(LA0, 0, 0); DS_A16(LA0, 1, 1); DS_A16(LA0, 2, 2); DS_A16(LA0, 3, 3);
            DS_B16(LB0, 0, 0); DS_B16(LB0, 1, 1);
        }
        BAR();
    }

    // Epilogue: 16x16 C/D layout col=lane&15, row=(lane>>4)*4+reg
#pragma unroll
    for (int mf = 0; mf < 8; ++mf) {
#pragma unroll
        for (int nf = 0; nf < 4; ++nf) {
#pragma unroll
            for (int r = 0; r < 4; ++r) {
                const int row = mBase + wm * 128 + mf * 16 + l4 * 4 + r;
                const int col = nBase + wn * 64 + nf * 16 + l15;
                C[(size_t)row * DIM_N + col] = acc4[mf][nf][r];
            }
        }
    }
}

// ---------------------------------------------------------------------------
// Fallback (only if workspace too small): direct fp32, one thread per output
// ---------------------------------------------------------------------------
__global__ __launch_bounds__(256) void naive_kernel(
        const float* __restrict__ x, const float* __restrict__ alphas,
        const int* __restrict__ bases, float* __restrict__ out) {
    const long o = (long)blockIdx.x * 256 + threadIdx.x;
    const int m = (int)(o >> 12), n = (int)(o & 4095);
    const float a0 = alphas[0], a1 = alphas[1], a2 = alphas[2], a3 = alphas[3];
    const float* xr = x + (long)m * DIM_K;
    const int* b0 = bases + (long)n * DIM_K;
    const int* b1 = b0 + BASE_STRIDE;
    const int* b2 = b1 + BASE_STRIDE;
    const int* b3 = b2 + BASE_STRIDE;
    float acc = 0.f;
    for (int i = 0; i < DIM_K; i++) {
        float w = a0 * b0[i] + a1 * b1[i] + a2 * b2[i] + a3 * b3[i];
        acc += xr[i] * w;
    }
    out[o] = acc;
}

extern "C" void kernel_launch(void* const* d_in, const int* in_sizes, int n_in,
                              void* d_out, int out_size, void* d_ws, size_t ws_size,
                              hipStream_t stream) {
    const float* x      = (const float*)d_in[0];
    const float* alphas = (const float*)d_in[1];
    const int*   bases  = (const int*)d_in[2];
    float* out = (float*)d_out;

    const size_t need = (size_t)2 * DIM_N * DIM_K + (size_t)2 * DIM_M * DIM_K; // 64 MB
    if (ws_size >= need) {
        unsigned short* Wb = (unsigned short*)d_ws;                    // [4096][4096] bf16
        unsigned short* Xb = (unsigned short*)d_ws + (size_t)DIM_N * DIM_K;
        prep_kernel<<<16384, 256, 0, stream>>>(bases, alphas, x, Wb, Xb);
        gemm_bt_kernel<<<dim3(DIM_N / 256, DIM_M / 256), 512, 0, stream>>>(Xb, Wb, out);
    } else {
        naive_kernel<<<(DIM_M * DIM_N) / 256, 256, 0, stream>>>(x, alphas, bases, out);
    }
}

// Round 8
// 526.560 us; speedup vs baseline: 1.0497x; 1.0049x over previous
//
#include <hip/hip_runtime.h>
#include <hip/hip_bf16.h>
#include <stdint.h>

// Problem constants (K=4, OUT=4096, IN=4096, B=2, S=2048)
#define DIM_M 4096   // B*S rows of x
#define DIM_N 4096   // OUT
#define DIM_K 4096   // IN
#define BASE_STRIDE (DIM_N * DIM_K)  // elements per basis
#define NT (DIM_K / 64)              // 64 K-tiles of BK=64

typedef __bf16 bf16x8 __attribute__((ext_vector_type(8)));
typedef float floatx4 __attribute__((ext_vector_type(4)));
typedef unsigned short ushort8 __attribute__((ext_vector_type(8)));

__device__ __forceinline__ unsigned short f2bf(float f) {
    uint32_t u = __float_as_uint(f);
    uint32_t r = (u + 0x7FFFu + ((u >> 16) & 1u)) >> 16;  // RNE
    return (unsigned short)r;
}

// ---------------------------------------------------------------------------
// Fused prologue (unchanged, verified): blocks [0,8192) build W_bf16;
// [8192,16384) convert x fp32 -> bf16. 8 elems/thread, 16B stores.
// ---------------------------------------------------------------------------
__global__ __launch_bounds__(256) void prep_kernel(
        const int* __restrict__ bases, const float* __restrict__ alphas,
        const float* __restrict__ x,
        unsigned short* __restrict__ Wb, unsigned short* __restrict__ Xb) {
    const int bid = blockIdx.x;
    if (bid < 8192) {
        const long e = ((long)bid * 256 + threadIdx.x) * 8;
        const float a0 = alphas[0], a1 = alphas[1], a2 = alphas[2], a3 = alphas[3];
        const int4 p0 = *(const int4*)(bases + e);
        const int4 p1 = *(const int4*)(bases + e + 4);
        const int4 q0 = *(const int4*)(bases + BASE_STRIDE + e);
        const int4 q1 = *(const int4*)(bases + BASE_STRIDE + e + 4);
        const int4 r0 = *(const int4*)(bases + 2L * BASE_STRIDE + e);
        const int4 r1 = *(const int4*)(bases + 2L * BASE_STRIDE + e + 4);
        const int4 s0 = *(const int4*)(bases + 3L * BASE_STRIDE + e);
        const int4 s1 = *(const int4*)(bases + 3L * BASE_STRIDE + e + 4);
        ushort8 o;
        o[0] = f2bf(a0 * p0.x + a1 * q0.x + a2 * r0.x + a3 * s0.x);
        o[1] = f2bf(a0 * p0.y + a1 * q0.y + a2 * r0.y + a3 * s0.y);
        o[2] = f2bf(a0 * p0.z + a1 * q0.z + a2 * r0.z + a3 * s0.z);
        o[3] = f2bf(a0 * p0.w + a1 * q0.w + a2 * r0.w + a3 * s0.w);
        o[4] = f2bf(a0 * p1.x + a1 * q1.x + a2 * r1.x + a3 * s1.x);
        o[5] = f2bf(a0 * p1.y + a1 * q1.y + a2 * r1.y + a3 * s1.y);
        o[6] = f2bf(a0 * p1.z + a1 * q1.z + a2 * r1.z + a3 * s1.z);
        o[7] = f2bf(a0 * p1.w + a1 * q1.w + a2 * r1.w + a3 * s1.w);
        *(ushort8*)(Wb + e) = o;
    } else {
        const long e = ((long)(bid - 8192) * 256 + threadIdx.x) * 8;
        const float4 v0 = *(const float4*)(x + e);
        const float4 v1 = *(const float4*)(x + e + 4);
        ushort8 o;
        o[0] = f2bf(v0.x); o[1] = f2bf(v0.y); o[2] = f2bf(v0.z); o[3] = f2bf(v0.w);
        o[4] = f2bf(v1.x); o[5] = f2bf(v1.y); o[6] = f2bf(v1.z); o[7] = f2bf(v1.w);
        *(ushort8*)(Xb + e) = o;
    }
}

// ---------------------------------------------------------------------------
// Main GEMM, 256x256 tile / BK=64 / 8-wave / 16x16x32 MFMA (R8).
//
// R8 = R7 (best, 529us total / ~127us gemm) + T1 XCD-aware block swizzle.
// R3-R7 lesson: intra-loop scheduling (read placement, barrier count, phase
// count, MFMA shape already tuned) is exhausted at ~1080 TF. Untouched axis:
// inter-block L2/L3 locality. Plain 2D grid + round-robin XCD dispatch
// (lin%8 -> XCD, m09) re-fetches each A-panel from L3 on all 8 XCDs
// (~288 MB L3->L2 per dispatch). Remap so each XCD owns a contiguous 4x8
// tile region: A-panels shared by 2 XCDs, B-panels by 4 (192 MB), and each
// K-step's slab working set (4 A + 8 B slabs = 384 KB) is L2-resident per
// XCD. Bijective: 256 blocks = 8 XCDs x 32 exact.
//   lin = y*16+x (dispatch order); xcd = lin&7; idx = lin>>3;
//   by = (xcd>>1)*4 + (idx>>3); bx = (xcd&1)*8 + (idx&7).
//
// R7 schedule (kept): every ds_read lands one phase before consumption:
//   P1: [reads B2-3]; stage A1(t+1); Q00 MFMA (frags from prev P4); BAR
//   P2: Q01 MFMA; [reads A4-7 post-cluster]; BAR
//   P3: stage B0(t+2); Q11 MFMA; BAR
//   P4: stage B1,A0(t+2); vmcnt(6); BAR; Q10 MFMA; [boundary reads]; BAR
//
// vmcnt ledger (verified): tile t halves issue B0@(t-2)P3, B1@(t-2)P4,
// A0@(t-2)P4, A1@(t-1)P1; at (t-1)P4 post-stage: 14 outstanding; vmcnt(6)
// retires the 8 oldest = tile t. Prologue 14 loads + vmcnt(6). Last iter
// vmcnt(0), group B skips boundary reads.
// WAR: every region's last ds_read drains >=1 barrier before its restage.
//
// LDS: lds[buf][A,B][half][128x64] = 128 KiB; global_load_lds w16 linear
// dest; chunk^(row&7) pre-swizzled source; read-side XOR. 16x16x32 layouts
// (HW-verified): A/B m(/n)=lane&15, k=(lane>>4)*8+j; C/D col=lane&15,
// row=(lane>>4)*4+reg.
// ---------------------------------------------------------------------------
#define MFMA16 __builtin_amdgcn_mfma_f32_16x16x32_bf16
#define BAR()   __builtin_amdgcn_s_barrier()
#define PRIO1() __builtin_amdgcn_s_setprio(1)
#define PRIO0() __builtin_amdgcn_s_setprio(0)

__device__ __forceinline__ void stage_half(const unsigned short* __restrict__ gb,
        int grow0, int kbase, unsigned short* ld, int wave, int lane) {
#pragma unroll
    for (int r = 0; r < 2; ++r) {
        const int row = wave * 16 + r * 8 + (lane >> 3);       // local row in half
        const int ch  = (lane & 7) ^ (row & 7);                // pre-swizzled src chunk
        const unsigned short* g = gb + (size_t)(grow0 + row) * DIM_K + kbase + ch * 8;
        unsigned short* d = ld + (wave * 16 + r * 8) * 64;     // wave-uniform LDS base
        __builtin_amdgcn_global_load_lds(
            (const __attribute__((address_space(1))) unsigned int*)((const void*)g),
            (__attribute__((address_space(3))) unsigned int*)((void*)d), 16, 0, 0);
    }
}

// Load one 16-row fragment pair (both k-halves) for A (row base MF*16)
#define DS_A16(LD, MF, SLOT)                                                          \
    do {                                                                              \
        aR[SLOT][0] = *(const bf16x8*)((LD) + ((MF) * 16 + l15) * 64 + cko2[0]);      \
        aR[SLOT][1] = *(const bf16x8*)((LD) + ((MF) * 16 + l15) * 64 + cko2[1]);      \
    } while (0)
// and for B (row base nloc + NF*16)
#define DS_B16(LD, NF, SLOT)                                                          \
    do {                                                                              \
        bR[SLOT][0] = *(const bf16x8*)((LD) + (nloc + (NF) * 16 + l15) * 64 + cko2[0]); \
        bR[SLOT][1] = *(const bf16x8*)((LD) + (nloc + (NF) * 16 + l15) * 64 + cko2[1]); \
    } while (0)
// One C-quadrant x K=64: 16 MFMA, kh-outer (dep distance 8 per acc chain)
#define MMQ(MB, NB)                                                                   \
    do { _Pragma("unroll") for (int kh = 0; kh < 2; ++kh)                             \
        _Pragma("unroll") for (int n = 0; n < 2; ++n)                                 \
            _Pragma("unroll") for (int m = 0; m < 4; ++m)                             \
                acc4[(MB) + m][(NB) + n] = MFMA16(aR[m][kh], bR[(NB) + n][kh],        \
                                                  acc4[(MB) + m][(NB) + n], 0, 0, 0); \
    } while (0)

__global__ __launch_bounds__(512, 2) void gemm_bt_kernel(
        const unsigned short* __restrict__ A, const unsigned short* __restrict__ Bt,
        float* __restrict__ C) {
    __shared__ __align__(16) unsigned short lds[2][2][2][128 * 64];  // 128 KiB

    const int t = threadIdx.x;
    const int wave = t >> 6, lane = t & 63;
    const int l15 = lane & 15, l4 = lane >> 4;     // 16x16 frag coords
    const int wm = wave >> 2;            // 0..1  -> A half / row block of 128
    const int wn = wave & 3;             // 0..3  -> 64-col block
    const int nloc = (wn & 1) * 64;      // row offset inside B half (wn>>1)

    // T1: XCD-aware remap (bijective, 256 = 8 XCD x 32). Dispatch order is
    // linear (x fastest); lin%8 = XCD (m09). Each XCD owns a 4(y) x 8(x)
    // contiguous tile region.
    const int lin = blockIdx.y * gridDim.x + blockIdx.x;
    const int xcd = lin & 7, idx = lin >> 3;
    const int by = (xcd >> 1) * 4 + (idx >> 3);
    const int bx = (xcd & 1) * 8 + (idx & 7);
    const int mBase = by * 256;
    const int nBase = bx * 256;

    const unsigned short* LA0 = &lds[0][0][wm][0];
    const unsigned short* LA1 = &lds[1][0][wm][0];
    const unsigned short* LB0 = &lds[0][1][wn >> 1][0];
    const unsigned short* LB1 = &lds[1][1][wn >> 1][0];

    int cko2[2];
#pragma unroll
    for (int kh = 0; kh < 2; ++kh) cko2[kh] = ((l4 + 4 * kh) ^ (l15 & 7)) * 8;

    floatx4 acc4[8][4] = {};
    bf16x8 aR[4][2], bR[4][2];

    // ---- prologue: tile0 -> buf0 (all 4 halves); tile1 -> buf1 (B0,B1,A0) ----
    stage_half(A,  mBase + 0,   0,  &lds[0][0][0][0], wave, lane);
    stage_half(A,  mBase + 128, 0,  &lds[0][0][1][0], wave, lane);
    stage_half(Bt, nBase + 0,   0,  &lds[0][1][0][0], wave, lane);
    stage_half(Bt, nBase + 128, 0,  &lds[0][1][1][0], wave, lane);
    stage_half(Bt, nBase + 0,   64, &lds[1][1][0][0], wave, lane);
    stage_half(Bt, nBase + 128, 64, &lds[1][1][1][0], wave, lane);
    stage_half(A,  mBase + 0,   64, &lds[1][0][0][0], wave, lane);
    asm volatile("s_waitcnt vmcnt(6)" ::: "memory");   // tile0 fully landed
    BAR();
    // boundary reads for tile0's Q00 (consumed in first PA1)
    DS_A16(LA0, 0, 0); DS_A16(LA0, 1, 1); DS_A16(LA0, 2, 2); DS_A16(LA0, 3, 3);
    DS_B16(LB0, 0, 0); DS_B16(LB0, 1, 1);

    for (int i = 0; i < NT / 2; ++i) {
        const bool more = (i < NT / 2 - 1);
        const int t1k = (2 * i + 1) * 64;
        const int t2k = (2 * i + 2) * 64;
        const int t3k = (2 * i + 3) * 64;

        // ================= group A: tile 2i from buf0 =================
        // P1: Q00 (frags pre-read at prev P4-end); pre-read B2-3 (free slots)
        DS_B16(LB0, 2, 2); DS_B16(LB0, 3, 3);
        stage_half(A, mBase + 128, t1k, &lds[1][0][1][0], wave, lane);   // A1(t+1)
        PRIO1(); MMQ(0, 0); PRIO0();
        BAR();
        // P2: Q01 (b2-3 landed under P1); post-read A4-7 into freed a0-3
        PRIO1(); MMQ(0, 2); PRIO0();
        DS_A16(LA0, 4, 0); DS_A16(LA0, 5, 1); DS_A16(LA0, 6, 2); DS_A16(LA0, 7, 3);
        BAR();
        // P3: Q11 (A4-7 landed under P2/barrier)
        if (more) stage_half(Bt, nBase + 0, t2k, &lds[0][1][0][0], wave, lane);
        PRIO1(); MMQ(4, 2); PRIO0();
        BAR();
        // P4: stage; vmcnt; mid-BAR (RAW for buf1); Q10; boundary reads (buf1)
        if (more) {
            stage_half(Bt, nBase + 128, t2k, &lds[0][1][1][0], wave, lane);
            stage_half(A,  mBase + 0,   t2k, &lds[0][0][0][0], wave, lane);
            asm volatile("s_waitcnt vmcnt(6)" ::: "memory");
        } else {
            asm volatile("s_waitcnt vmcnt(0)" ::: "memory");
        }
        BAR();
        PRIO1(); MMQ(4, 0); PRIO0();
        DS_A16(LA1, 0, 0); DS_A16(LA1, 1, 1); DS_A16(LA1, 2, 2); DS_A16(LA1, 3, 3);
        DS_B16(LB1, 0, 0); DS_B16(LB1, 1, 1);
        BAR();

        // ================= group B: tile 2i+1 from buf1 =================
        // P1
        DS_B16(LB1, 2, 2); DS_B16(LB1, 3, 3);
        if (more) stage_half(A, mBase + 128, t2k, &lds[0][0][1][0], wave, lane); // A1(t+2)
        PRIO1(); MMQ(0, 0); PRIO0();
        BAR();
        // P2
        PRIO1(); MMQ(0, 2); PRIO0();
        DS_A16(LA1, 4, 0); DS_A16(LA1, 5, 1); DS_A16(LA1, 6, 2); DS_A16(LA1, 7, 3);
        BAR();
        // P3
        if (more) stage_half(Bt, nBase + 0, t3k, &lds[1][1][0][0], wave, lane);
        PRIO1(); MMQ(4, 2); PRIO0();
        BAR();
        // P4
        if (more) {
            stage_half(Bt, nBase + 128, t3k, &lds[1][1][1][0], wave, lane);
            stage_half(A,  mBase + 0,   t3k, &lds[1][0][0][0], wave, lane);
            asm volatile("s_waitcnt vmcnt(6)" ::: "memory");
        } else {
            asm volatile("s_waitcnt vmcnt(0)" ::: "memory");
        }
        BAR();
        PRIO1(); MMQ(4, 0); PRIO0();
        if (more) {
            DS_A16(LA0, 0, 0); DS_A16(LA0, 1, 1); DS_A16(LA0, 2, 2); DS_A16(LA0, 3, 3);
            DS_B16(LB0, 0, 0); DS_B16(LB0, 1, 1);
        }
        BAR();
    }

    // Epilogue: 16x16 C/D layout col=lane&15, row=(lane>>4)*4+reg
#pragma unroll
    for (int mf = 0; mf < 8; ++mf) {
#pragma unroll
        for (int nf = 0; nf < 4; ++nf) {
#pragma unroll
            for (int r = 0; r < 4; ++r) {
                const int row = mBase + wm * 128 + mf * 16 + l4 * 4 + r;
                const int col = nBase + wn * 64 + nf * 16 + l15;
                C[(size_t)row * DIM_N + col] = acc4[mf][nf][r];
            }
        }
    }
}

// ---------------------------------------------------------------------------
// Fallback (only if workspace too small): direct fp32, one thread per output
// ---------------------------------------------------------------------------
__global__ __launch_bounds__(256) void naive_kernel(
        const float* __restrict__ x, const float* __restrict__ alphas,
        const int* __restrict__ bases, float* __restrict__ out) {
    const long o = (long)blockIdx.x * 256 + threadIdx.x;
    const int m = (int)(o >> 12), n = (int)(o & 4095);
    const float a0 = alphas[0], a1 = alphas[1], a2 = alphas[2], a3 = alphas[3];
    const float* xr = x + (long)m * DIM_K;
    const int* b0 = bases + (long)n * DIM_K;
    const int* b1 = b0 + BASE_STRIDE;
    const int* b2 = b1 + BASE_STRIDE;
    const int* b3 = b2 + BASE_STRIDE;
    float acc = 0.f;
    for (int i = 0; i < DIM_K; i++) {
        float w = a0 * b0[i] + a1 * b1[i] + a2 * b2[i] + a3 * b3[i];
        acc += xr[i] * w;
    }
    out[o] = acc;
}

extern "C" void kernel_launch(void* const* d_in, const int* in_sizes, int n_in,
                              void* d_out, int out_size, void* d_ws, size_t ws_size,
                              hipStream_t stream) {
    const float* x      = (const float*)d_in[0];
    const float* alphas = (const float*)d_in[1];
    const int*   bases  = (const int*)d_in[2];
    float* out = (float*)d_out;

    const size_t need = (size_t)2 * DIM_N * DIM_K + (size_t)2 * DIM_M * DIM_K; // 64 MB
    if (ws_size >= need) {
        unsigned short* Wb = (unsigned short*)d_ws;                    // [4096][4096] bf16
        unsigned short* Xb = (unsigned short*)d_ws + (size_t)DIM_N * DIM_K;
        prep_kernel<<<16384, 256, 0, stream>>>(bases, alphas, x, Wb, Xb);
        gemm_bt_kernel<<<dim3(DIM_N / 256, DIM_M / 256), 512, 0, stream>>>(Xb, Wb, out);
    } else {
        naive_kernel<<<(DIM_M * DIM_N) / 256, 256, 0, stream>>>(x, alphas, bases, out);
    }
}